// Round 1
// 125.239 us; speedup vs baseline: 1.0379x; 1.0379x over previous
//
#include <hip/hip_runtime.h>
#include <math.h>

#define B_ 4
#define S_ 2048
#define D_ 512
#define H_ 8
#define DH_ 64
#define BH_ (B_*H_)
#define SCALE 0.1803368801111243f   // log2(e)/sqrt(64)

typedef __attribute__((ext_vector_type(4)))  float f32x4;
typedef __attribute__((ext_vector_type(16))) float f32x16;
typedef __attribute__((ext_vector_type(8)))  short bf16x8;
typedef __attribute__((ext_vector_type(4)))  uint  u32x4;

__device__ inline uint rnepk(float a, float b) {
    uint ua = __builtin_bit_cast(uint, a), ub = __builtin_bit_cast(uint, b);
    ua += 0x7FFFu + ((ua >> 16) & 1u);
    ub += 0x7FFFu + ((ub >> 16) & 1u);
    return (ua >> 16) | (ub & 0xFFFF0000u);
}
__device__ inline uint truncpk(float lo, float hi) {   // 1 v_perm_b32
    return __builtin_amdgcn_perm(__builtin_bit_cast(uint, hi),
                                 __builtin_bit_cast(uint, lo), 0x07060302u);
}
__device__ inline f32x16 zero16() {
    f32x16 z;
    #pragma unroll
    for (int i = 0; i < 16; ++i) z[i] = 0.f;
    return z;
}
__device__ inline bf16x8 pack8(f32x4 a, f32x4 c) {
    u32x4 u;
    u.x = rnepk(a[0], a[1]); u.y = rnepk(a[2], a[3]);
    u.z = rnepk(c[0], c[1]); u.w = rnepk(c[2], c[3]);
    return __builtin_bit_cast(bf16x8, u);
}

// (lane,lane^32) quad exchange (validated: R6's P-transform passed)
#if __has_builtin(__builtin_amdgcn_permlane32_swap)
__device__ inline void lane32swap(uint& a, uint& b) {
    typedef __attribute__((ext_vector_type(2))) uint u32x2;
    u32x2 r = __builtin_amdgcn_permlane32_swap(a, b, false, false);
    a = r.x; b = r.y;
}
#else
__device__ inline void lane32swap(uint& a, uint& b) {
    const int l5 = (threadIdx.x & 63) >> 5;
    uint send = l5 ? a : b;
    uint recv = __shfl_xor(send, 32);
    uint an = l5 ? recv : a;
    uint bn = l5 ? b : recv;
    a = an; b = bn;
}
#endif

// async global->LDS DMA, 16B/lane: LDS dest = wave-uniform base + lane*16
__device__ inline void dma16(const ushort* g, ushort* l) {
    __builtin_amdgcn_global_load_lds(
        (const __attribute__((address_space(1))) unsigned int*)g,
        (__attribute__((address_space(3))) unsigned int*)l, 16, 0, 0);
}

// ---------------------------------------------------------------------------
// Kernel 0: weight prep. Converts Wq/Wk/Wv (f32 [H][64][64]) to fragment-
// linear bf16, exactly the per-lane layout qkv_mfma's MFMA A/B operand wants:
//   Wf[((proj*8+h)*8 + (et*4+st))*512 + lane*8 + j]
//     = rne_bf16( W[h][et*32+l31][st*16+l5*8+j] )
// Same rnepk rounding as before -> qkv results bit-identical. Runs once per
// launch (~192 KB out); kills the 64x-redundant strided f32 W loads + pack
// VALU that dominated qkv.
// ---------------------------------------------------------------------------
__global__ __launch_bounds__(256)
void prep_w(const float* __restrict__ Wq, const float* __restrict__ Wk,
            const float* __restrict__ Wv, ushort* __restrict__ Wf)
{
    const int pb = blockIdx.x;                 // 0..23 = proj*8 + h
    const int proj = pb >> 3, h = pb & 7;
    const float* W = (proj == 0 ? Wq : proj == 1 ? Wk : Wv) + h * DH_ * DH_;
    #pragma unroll
    for (int it = 0; it < 2; ++it) {
        const int slot = threadIdx.x + it * 256;   // 512 lane-slots
        const int c = slot >> 6, lane = slot & 63;
        const int l31 = lane & 31, l5 = lane >> 5;
        const int et = c >> 2, st = c & 3;
        const float* wr = W + (et * 32 + l31) * DH_ + st * 16 + l5 * 8;
        bf16x8 v = pack8(*(const f32x4*)wr, *(const f32x4*)(wr + 4));
        *(bf16x8*)(Wf + ((size_t)pb * 8 + c) * 512 + lane * 8) = v;
    }
}

// ---------------------------------------------------------------------------
// Kernel 1: QKV projection, 32x32x16 MFMA, emitting FRAGMENT-LINEAR layouts:
//   Qf[bh][qt(64)][st(4)][lane*8]   (lane = l5*32+l31: q=qt*32+l31, dh=st*16+l5*8)
//   Kf[bh][kt(32)][g(2)][st(4)][lane*8]  (key=g*32+l31, dh=st*16+l5*8)
//   Vf[bh][kt(32)][dht(2)][st(4)][lane*8] (dh=dht*32+l31, key=st*16+l5*8)
// W fragments now come pre-packed bf16 from Wf (coalesced 16B/lane, 24 KB,
// L1-resident). grid (32, 16), 256 thr. One barrier (V transpose share).
// ---------------------------------------------------------------------------
__global__ __launch_bounds__(256, 2)
void qkv_mfma(const float* __restrict__ x,
              const float* __restrict__ bq, const float* __restrict__ bk,
              const float* __restrict__ bv, const ushort* __restrict__ Wf,
              ushort* __restrict__ Qf, ushort* __restrict__ Kf,
              ushort* __restrict__ Vf)
{
    const int bh = blockIdx.x, b = bh >> 3, h = bh & 7;
    const int sblk = blockIdx.y, s0 = sblk * 128;
    const int tid = threadIdx.x;
    const int w = tid >> 6, lane = tid & 63, l31 = lane & 31, l5 = lane >> 5;

    __shared__ __align__(16) ushort bnc[4][2560];    // per-wave [s][e] stride 72
    __shared__ __align__(16) ushort vsh[64 * 136];   // block-shared Vt [dh][s128]
    ushort* mybnc = bnc[w];

    const ushort* wqb = Wf + ((size_t)(0 * 8 + h)) * 8 * 512;
    const ushort* wkb = Wf + ((size_t)(1 * 8 + h)) * 8 * 512;
    const ushort* wvb = Wf + ((size_t)(2 * 8 + h)) * 8 * 512;

    // ---- x fragments straight from global ----
    const int srow = w * 32 + l31;
    const float* xr = x + ((size_t)(b * S_ + s0 + srow)) * D_ + h * DH_;
    bf16x8 xf[4];
    #pragma unroll
    for (int st = 0; st < 4; ++st)
        xf[st] = pack8(*(const f32x4*)(xr + st * 16 + l5 * 8),
                       *(const f32x4*)(xr + st * 16 + l5 * 8 + 4));

    // ---- K: C[e][s] (A=Wk,B=x) -> bounce [s][e] -> fragment emit ----
    {
        bf16x8 wf[2][4];
        #pragma unroll
        for (int et = 0; et < 2; ++et)
            #pragma unroll
            for (int st = 0; st < 4; ++st)
                wf[et][st] = *(const bf16x8*)(wkb + (et * 4 + st) * 512 + lane * 8);
        #pragma unroll
        for (int et = 0; et < 2; ++et) {
            f32x16 acc = zero16();
            #pragma unroll
            for (int st = 0; st < 4; ++st)
                acc = __builtin_amdgcn_mfma_f32_32x32x16_bf16(wf[et][st], xf[st], acc, 0, 0, 0);
            #pragma unroll
            for (int rg = 0; rg < 4; ++rg) {
                float4 b4 = *(const float4*)(bk + h * DH_ + et * 32 + rg * 8 + l5 * 4);
                uint2 pk;
                pk.x = rnepk(acc[rg * 4 + 0] + b4.x, acc[rg * 4 + 1] + b4.y);
                pk.y = rnepk(acc[rg * 4 + 2] + b4.z, acc[rg * 4 + 3] + b4.w);
                *(uint2*)(mybnc + l31 * 72 + et * 32 + rg * 8 + l5 * 4) = pk;
            }
        }
        const int kt = sblk * 2 + (w >> 1), g = w & 1;
        ushort* kd = Kf + (((size_t)(bh * 32 + kt)) * 2 + g) * 2048;
        #pragma unroll
        for (int st = 0; st < 4; ++st) {
            uint4 v = *(const uint4*)(mybnc + l31 * 72 + st * 16 + l5 * 8);
            *(uint4*)(kd + st * 512 + lane * 8) = v;
        }
    }

    // ---- Q: same, with bias+SCALE, emit tile qt = sblk*4 + w ----
    {
        bf16x8 wf[2][4];
        #pragma unroll
        for (int et = 0; et < 2; ++et)
            #pragma unroll
            for (int st = 0; st < 4; ++st)
                wf[et][st] = *(const bf16x8*)(wqb + (et * 4 + st) * 512 + lane * 8);
        #pragma unroll
        for (int et = 0; et < 2; ++et) {
            f32x16 acc = zero16();
            #pragma unroll
            for (int st = 0; st < 4; ++st)
                acc = __builtin_amdgcn_mfma_f32_32x32x16_bf16(wf[et][st], xf[st], acc, 0, 0, 0);
            #pragma unroll
            for (int rg = 0; rg < 4; ++rg) {
                float4 b4 = *(const float4*)(bq + h * DH_ + et * 32 + rg * 8 + l5 * 4);
                uint2 pk;
                pk.x = rnepk((acc[rg * 4 + 0] + b4.x) * SCALE, (acc[rg * 4 + 1] + b4.y) * SCALE);
                pk.y = rnepk((acc[rg * 4 + 2] + b4.z) * SCALE, (acc[rg * 4 + 3] + b4.w) * SCALE);
                *(uint2*)(mybnc + l31 * 72 + et * 32 + rg * 8 + l5 * 4) = pk;
            }
        }
        ushort* qd = Qf + ((size_t)(bh * 64 + sblk * 4 + w)) * 2048;
        #pragma unroll
        for (int st = 0; st < 4; ++st) {
            uint4 v = *(const uint4*)(mybnc + l31 * 72 + st * 16 + l5 * 8);
            *(uint4*)(qd + st * 512 + lane * 8) = v;
        }
    }

    // ---- V: C[s][e] (A=x,B=Wv) -> block-shared Vt[dh][s128] -> frag emit ----
    {
        bf16x8 wf[2][4];
        #pragma unroll
        for (int et = 0; et < 2; ++et)
            #pragma unroll
            for (int st = 0; st < 4; ++st)
                wf[et][st] = *(const bf16x8*)(wvb + (et * 4 + st) * 512 + lane * 8);
        #pragma unroll
        for (int et = 0; et < 2; ++et) {
            f32x16 acc = zero16();
            #pragma unroll
            for (int st = 0; st < 4; ++st)
                acc = __builtin_amdgcn_mfma_f32_32x32x16_bf16(xf[st], wf[et][st], acc, 0, 0, 0);
            const float bb = bv[h * DH_ + et * 32 + l31];
            #pragma unroll
            for (int rg = 0; rg < 4; ++rg) {
                uint2 pk;
                pk.x = rnepk(acc[rg * 4 + 0] + bb, acc[rg * 4 + 1] + bb);
                pk.y = rnepk(acc[rg * 4 + 2] + bb, acc[rg * 4 + 3] + bb);
                // Vt[dh = et*32+l31][s = w*32 + rg*8 + l5*4 + {0..3}]
                *(uint2*)(vsh + (et * 32 + l31) * 136 + w * 32 + rg * 8 + l5 * 4) = pk;
            }
        }
        __syncthreads();
        #pragma unroll
        for (int i = 0; i < 4; ++i) {
            const int c = w * 4 + i;                 // 16 chunks: [ktl][dht][st]
            const int ktl = c >> 3, dht = (c >> 2) & 1, st = c & 3;
            uint4 v = *(const uint4*)(vsh + (dht * 32 + l31) * 136 + ktl * 64 + st * 16 + l5 * 8);
            *(uint4*)(Vf + (((size_t)(bh * 32 + sblk * 2 + ktl)) * 2 + dht) * 2048
                      + st * 512 + lane * 8) = v;
        }
    }
}

// ---------------------------------------------------------------------------
// Kernel 2: flash, 32x32x16 MFMA, 64 q/wave, split-K parity. grid 512 =
// 32 bh x 16 qblk (128 q/block), 4 waves: w0/w1 even K-tiles (q-halves 0/1),
// w2/w3 odd tiles. No online max -> partials merge by pure addition. K/V
// staged via global_load_lds dwordx4 into fragment-linear LDS (zero VALU
// staging); fragment reads are base+lane*16 (conflict-free). One barrier per
// step (2 K-tiles). s_setprio(1) wraps MFMA clusters (T5). End: partner merge
// through LDS, normalize, coalesced out.
// ---------------------------------------------------------------------------
__global__ __launch_bounds__(256, 2)
void flash_mfma(const ushort* __restrict__ Qf, const ushort* __restrict__ Kf,
                const ushort* __restrict__ Vf, float* __restrict__ out)
{
    const int blk = blockIdx.x;
    const int bh = blk & 31, qblk = blk >> 5;
    const int b = bh >> 3, h = bh & 7;
    const int tid = threadIdx.x;
    const int w = tid >> 6, lane = tid & 63, l31 = lane & 31, l5 = lane >> 5;
    const int p = w >> 1, qh = w & 1;    // K-parity, q-half

    // dbuf: buf s at s*16384 ush (32KB): [Kev 4096][Vev 4096][Kod 4096][Vod 4096]
    // epilogue overlays: 2 x (64q x 68 f32) + lsA = 35328 B
    __shared__ __align__(16) ushort lds_u[32768];    // 65536 B

    const ushort* kvsrc = (w & 1) ? (Vf + (size_t)bh * 32 * 4096)
                                  : (Kf + (size_t)bh * 32 * 4096);

    // ---- prologue: DMA step-0 tiles into buf0 (wave w stages region w) ----
    {
        const ushort* gb = kvsrc + (size_t)p * 4096;     // tile = 0+p
        ushort* ld = lds_u + w * 4096;
        #pragma unroll
        for (int i = 0; i < 8; ++i)
            dma16(gb + i * 512 + lane * 8, ld + i * 512);
    }

    // ---- Q B-frags (coalesced from Qf) ----
    bf16x8 qf[2][4];
    #pragma unroll
    for (int qt = 0; qt < 2; ++qt)
        #pragma unroll
        for (int st = 0; st < 4; ++st)
            qf[qt][st] = *(const bf16x8*)(Qf + ((size_t)(bh * 64 + qblk * 4 + qh * 2 + qt)) * 2048
                                          + st * 512 + lane * 8);

    f32x16 O[2][2];                      // [dht][qt], O^T cols q = qt*32+l31
    #pragma unroll
    for (int i = 0; i < 2; ++i)
        #pragma unroll
        for (int j = 0; j < 2; ++j) O[i][j] = zero16();
    float lsum[2] = {0.f, 0.f};

    for (int step = 0; step < 16; ++step) {
        __syncthreads();                 // drains DMAs for buf[cur]
        ushort* cbuf = lds_u + (step & 1) * 16384;
        if (step < 15) {                 // DMA step+1 into other buffer
            const ushort* gb = kvsrc + (size_t)(2 * (step + 1) + p) * 4096;
            ushort* ld = lds_u + ((step + 1) & 1) * 16384 + w * 4096;
            #pragma unroll
            for (int i = 0; i < 8; ++i)
                dma16(gb + i * 512 + lane * 8, ld + i * 512);
        }
        const ushort* kreg = cbuf + p * 8192;
        const ushort* vreg = kreg + 4096;

        // ---- S^T = K.Q^T, exp, pack, quad exchange -> pf ----
        bf16x8 pf[2][4];
        #pragma unroll
        for (int g = 0; g < 2; ++g) {
            bf16x8 kf[4];
            #pragma unroll
            for (int st = 0; st < 4; ++st)
                kf[st] = *(const bf16x8*)(kreg + (g * 4 + st) * 512 + lane * 8);
            #pragma unroll
            for (int qt = 0; qt < 2; ++qt) {
                f32x16 sc_ = zero16();
                __builtin_amdgcn_s_setprio(1);
                #pragma unroll
                for (int st = 0; st < 4; ++st)
                    sc_ = __builtin_amdgcn_mfma_f32_32x32x16_bf16(kf[st], qf[qt][st], sc_, 0, 0, 0);
                __builtin_amdgcn_s_setprio(0);
                uint pr[8];
                #pragma unroll
                for (int rg = 0; rg < 4; ++rg) {
                    float p0 = __builtin_amdgcn_exp2f(sc_[rg * 4 + 0]);
                    float p1 = __builtin_amdgcn_exp2f(sc_[rg * 4 + 1]);
                    float p2 = __builtin_amdgcn_exp2f(sc_[rg * 4 + 2]);
                    float p3 = __builtin_amdgcn_exp2f(sc_[rg * 4 + 3]);
                    lsum[qt] += (p0 + p1) + (p2 + p3);
                    pr[2 * rg + 0] = truncpk(p0, p1);
                    pr[2 * rg + 1] = truncpk(p2, p3);
                }
                #pragma unroll
                for (int pp = 0; pp < 2; ++pp) {
                    lane32swap(pr[4 * pp + 0], pr[4 * pp + 2]);
                    lane32swap(pr[4 * pp + 1], pr[4 * pp + 3]);
                    u32x4 u; u.x = pr[4 * pp + 0]; u.y = pr[4 * pp + 1];
                    u.z = pr[4 * pp + 2]; u.w = pr[4 * pp + 3];
                    pf[qt][g * 2 + pp] = __builtin_bit_cast(bf16x8, u);
                }
            }
        }

        // ---- PV: O^T[dht][qt] += Vt.P^T ----
        #pragma unroll
        for (int dht = 0; dht < 2; ++dht) {
            bf16x8 vf[4];
            #pragma unroll
            for (int st = 0; st < 4; ++st)
                vf[st] = *(const bf16x8*)(vreg + (dht * 4 + st) * 512 + lane * 8);
            __builtin_amdgcn_s_setprio(1);
            #pragma unroll
            for (int qt = 0; qt < 2; ++qt)
                #pragma unroll
                for (int st = 0; st < 4; ++st)
                    O[dht][qt] = __builtin_amdgcn_mfma_f32_32x32x16_bf16(vf[st], pf[qt][st],
                                                                          O[dht][qt], 0, 0, 0);
            __builtin_amdgcn_s_setprio(0);
        }
    }

    // ---- merge parity partners (pure add: no online max), normalize ----
    #pragma unroll
    for (int qt = 0; qt < 2; ++qt) lsum[qt] += __shfl_xor(lsum[qt], 32);

    __syncthreads();                     // all loop reads done before overlay
    float* mb = (float*)lds_u;           // region qh: 64x68 f32; lsA at +8704
    float* reg = mb + qh * 4352;
    float* lsA = mb + 2 * 4352;

    if (p == 1) {                        // odd-parity waves publish partials
        #pragma unroll
        for (int dht = 0; dht < 2; ++dht)
            #pragma unroll
            for (int qt = 0; qt < 2; ++qt)
                #pragma unroll
                for (int rg = 0; rg < 4; ++rg) {
                    f32x4 v4;
                    v4[0] = O[dht][qt][rg * 4 + 0];
                    v4[1] = O[dht][qt][rg * 4 + 1];
                    v4[2] = O[dht][qt][rg * 4 + 2];
                    v4[3] = O[dht][qt][rg * 4 + 3];
                    *(f32x4*)(reg + (qt * 32 + l31) * 68 + dht * 32 + rg * 8 + l5 * 4) = v4;
                }
        if (l5 == 0) {
            #pragma unroll
            for (int qt = 0; qt < 2; ++qt)
                lsA[qh * 64 + qt * 32 + l31] = lsum[qt];
        }
    }
    __syncthreads();
    if (p == 0) {                        // even-parity waves merge + finalize
        float linv[2];
        #pragma unroll
        for (int qt = 0; qt < 2; ++qt)
            linv[qt] = 1.0f / (lsum[qt] + lsA[qh * 64 + qt * 32 + l31]);
        #pragma unroll
        for (int dht = 0; dht < 2; ++dht)
            #pragma unroll
            for (int qt = 0; qt < 2; ++qt)
                #pragma unroll
                for (int rg = 0; rg < 4; ++rg) {
                    float* a = reg + (qt * 32 + l31) * 68 + dht * 32 + rg * 8 + l5 * 4;
                    f32x4 part = *(const f32x4*)a;
                    f32x4 v4;
                    v4[0] = (O[dht][qt][rg * 4 + 0] + part[0]) * linv[qt];
                    v4[1] = (O[dht][qt][rg * 4 + 1] + part[1]) * linv[qt];
                    v4[2] = (O[dht][qt][rg * 4 + 2] + part[2]) * linv[qt];
                    v4[3] = (O[dht][qt][rg * 4 + 3] + part[3]) * linv[qt];
                    *(f32x4*)a = v4;
                }
    }
    __syncthreads();

    // ---- cooperative coalesced store: 128 rows x 16 chunks of 16B ----
    const int q0 = qblk * 128;
    #pragma unroll
    for (int i = 0; i < 8; ++i) {
        const int slot = tid + 256 * i;
        const int r = slot >> 4, c = slot & 15;
        f32x4 v = *(const f32x4*)(mb + (r >> 6) * 4352 + (r & 63) * 68 + c * 4);
        *(f32x4*)(out + ((size_t)(b * S_ + q0 + r)) * D_ + h * DH_ + c * 4) = v;
    }
}

extern "C" void kernel_launch(void* const* d_in, const int* in_sizes, int n_in,
                              void* d_out, int out_size, void* d_ws, size_t ws_size,
                              hipStream_t stream) {
    const float* x  = (const float*)d_in[0];
    const float* Wq = (const float*)d_in[1];
    const float* bq = (const float*)d_in[2];
    const float* Wk = (const float*)d_in[3];
    const float* bk = (const float*)d_in[4];
    const float* Wv = (const float*)d_in[5];
    const float* bv = (const float*)d_in[6];
    float* outp = (float*)d_out;

    ushort* Qf = (ushort*)d_ws;                        // frag-linear, 8 MB
    ushort* Kf = Qf + (size_t)BH_ * S_ * DH_;          // 8 MB
    ushort* Vf = Kf + (size_t)BH_ * S_ * DH_;          // 8 MB
    ushort* Wfb = Vf + (size_t)BH_ * S_ * DH_;         // 192 KB bf16 W frags

    prep_w<<<dim3(24), 256, 0, stream>>>(Wq, Wk, Wv, Wfb);
    qkv_mfma<<<dim3(BH_, S_ / 128), 256, 0, stream>>>(x, bq, bk, bv, Wfb,
                                                      Qf, Kf, Vf);
    flash_mfma<<<dim3(32 * 16), 256, 0, stream>>>(Qf, Kf, Vf, outp);
}